// Round 8
// baseline (73.811 us; speedup 1.0000x reference)
//
#include <hip/hip_runtime.h>

// SparseMaskedLinear: out[b,co] = bias[co] + sum_e in[b,ci_e]*w_e  (B=64, dims 2000)
// Dense reformulation: W[ci][co] = sum w_e;  out = in[:, :2000] @ W + bias.
// Round-8: DETERMINISTIC scatter. Each block owns fixed slabs binned[blk][bin][0:64]
// -> no cursor atomics, no reserve barrier (round 5-7 evidence: that path was ~25us
// of atomic round-trips). LDS-staged 128B-aligned flush, padded with zero-weight
// no-op records; per-(blk,bin) counts table; bin_build flattens via LDS scan +
// binary search. Rare r>=CAP records go to a tiny global overflow list.

#define ROWS8 8
#define NB 256                 // bin slots (nbins <= 256)
#define E_PT 8
#define TPB_SC 1024
#define SEG6 (TPB_SC * E_PT)   // 8192 edges per scatter block
#define SCAP 48                // LDS-staged records per bin (mean 32.8, +2.7 sigma)
#define CAP 64                 // slab size per (blk,bin); P(c>64) ~ 2e-8 per cell
#define NSEGP 512              // max scatter blocks (gate: nseg <= NSEGP)
#define OVF_CAP 4096

#define TILE_O 64
#define KS 64
#define SLICES 16
#define PSTRIDE 2048

// ---- int64-vs-int32 materialization detect (values < 2048 => int64 high words all 0)
__global__ void smw_detect(const unsigned int* __restrict__ m, int* __restrict__ flag) {
    if (blockIdx.x == 0 && threadIdx.x == 0) {
        unsigned int orv = 0u;
        for (int k = 0; k < 64; ++k) orv |= m[2 * k + 1];
        *flag = (orv == 0u) ? 1 : 0;   // 1 => int64 layout
    }
}

// ---- Phase 1: deterministic scatter. LDS rank -> stage (r<SCAP) or direct slab
// store (SCAP<=r<CAP, rare) or overflow list (r>=CAP, ~never). One barrier, then
// 16-lane groups flush each bin's run as full 128B lines (pad = {0, 0.0f}).
__global__ __launch_bounds__(TPB_SC) void smw_scatter6(
    const int* __restrict__ mask, const float* __restrict__ wgt,
    const int* __restrict__ flag, int2* __restrict__ binned,
    int* __restrict__ counts, int2* __restrict__ ovf, int* __restrict__ ovf_cnt,
    int n_edges, int krows, int nbins) {
    extern __shared__ int smem[];
    int*  hist  = smem;                       // NB ints
    int2* stage = (int2*)(smem + NB);         // NB * SCAP int2 (96 KB)
    const int tid = threadIdx.x;
    const int blk = blockIdx.x;
    const long long e0 = (long long)blk * SEG6;
    if (tid < NB) hist[tid] = 0;
    __syncthreads();
    const bool is64 = (*flag != 0);

    for (int i = 0; i < E_PT; ++i) {
        long long e = e0 + (long long)i * TPB_SC + tid;
        if (e < n_edges) {
            int ci, co;
            if (is64) { int4 m = ((const int4*)mask)[e]; ci = m.x; co = m.z; }
            else      { int2 m = ((const int2*)mask)[e]; ci = m.x; co = m.y; }
            if ((unsigned)ci < (unsigned)krows) {
                int b = ci >> 3;               // 8 rows per bin
                int2 rec = make_int2((int)((((unsigned)(ci & 7)) << 16) |
                                           (unsigned)(co & 0xFFFF)),
                                     __float_as_int(wgt[e]));
                int r = atomicAdd(&hist[b], 1);            // LDS rank
                if (r < SCAP) {
                    stage[b * SCAP + r] = rec;
                } else if (r < CAP) {                      // rare mid-range
                    binned[((long long)blk * NB + b) * CAP + r] = rec;
                } else {                                   // ~never
                    int j = atomicAdd(ovf_cnt, 1);
                    if (j < OVF_CAP)
                        ovf[j] = make_int2((ci << 16) | (co & 0xFFFF),
                                           __float_as_int(wgt[e]));
                }
            }
        }
    }
    __syncthreads();
    // coalesced aligned flush: 64 groups x 16 lanes
    const int grp = tid >> 4;
    const int ln  = tid & 15;
    for (int b = grp; b < nbins; b += (TPB_SC / 16)) {
        int c  = hist[b];
        int cS = c < SCAP ? c : SCAP;
        int cp = (c + 15) & ~15; if (cp > CAP) cp = CAP;   // padded to 128B lines
        long long base = ((long long)blk * NB + b) * CAP;
        for (int k = ln; k < cp; k += 16) {
            if (k < cS)       binned[base + k] = stage[b * SCAP + k];
            else if (k >= c)  binned[base + k] = make_int2(0, 0);  // no-op pad
            // cS <= k < min(c,CAP): already written directly above
        }
        if (ln == 0) counts[b * NSEGP + blk] = cp;
    }
}

// ---- Phase 2: per-bin exclusive build of 8 W-rows. Flatten all blocks' runs via
// LDS inclusive scan + per-record binary search (coalesced slab reads).
__global__ __launch_bounds__(512) void smw_bin_build4(
    const int2* __restrict__ binned, const int* __restrict__ counts,
    const int2* __restrict__ ovf, const int* __restrict__ ovf_cnt,
    float* __restrict__ W, int out_f, int krows, int nseg) {
    extern __shared__ float tile[];                 // ROWS8 * out_f floats
    __shared__ int sc[NSEGP];
    const int tid = threadIdx.x;
    const int bin = blockIdx.x;
    const int tile_elems = ROWS8 * out_f;
    {
        float4* t4 = (float4*)tile;
        int n4 = tile_elems >> 2;
        for (int t = tid; t < n4; t += 512) t4[t] = make_float4(0.f, 0.f, 0.f, 0.f);
    }
    // load padded counts for this bin and scan (512 threads, NSEGP=512 slots)
    int c0 = (tid < nseg) ? counts[bin * NSEGP + tid] : 0;
    sc[tid] = c0;
    __syncthreads();
    for (int off = 1; off < NSEGP; off <<= 1) {
        int v = sc[tid];
        if (tid >= off) v += sc[tid - off];
        __syncthreads();
        sc[tid] = v;
        __syncthreads();
    }
    const int total = sc[NSEGP - 1];
    for (int i = tid; i < total; i += 512) {
        int lo = 0, hi = NSEGP - 1;                  // first blk with sc[blk] > i
        #pragma unroll
        for (int s = 0; s < 9; ++s) {
            int mid = (lo + hi) >> 1;
            if (sc[mid] > i) hi = mid; else lo = mid + 1;
        }
        int blk = lo;
        int off_in = i - (blk ? sc[blk - 1] : 0);
        int2 rec = binned[((long long)blk * NB + bin) * CAP + off_in];
        unsigned k = (unsigned)rec.x;
        atomicAdd(&tile[(int)(k >> 16) * out_f + (int)(k & 0xFFFFu)],
                  __int_as_float(rec.y));           // pads add +0.0 to tile[0]
    }
    // overflow records (normally zero)
    int no = *ovf_cnt; if (no > OVF_CAP) no = OVF_CAP;
    for (int i = tid; i < no; i += 512) {
        int2 r = ovf[i];
        int ci = ((unsigned)r.x) >> 16;
        if ((ci >> 3) == bin)
            atomicAdd(&tile[(ci & 7) * out_f + (r.x & 0xFFFF)], __int_as_float(r.y));
    }
    __syncthreads();
    #pragma unroll
    for (int r = 0; r < ROWS8; ++r) {
        int row = bin * ROWS8 + r;
        if (row >= krows) break;
        float* dst = W + (long long)row * out_f;
        const float* s = tile + r * out_f;
        for (int c = tid * 4; c < out_f; c += 2048)
            *(float4*)&dst[c] = *(const float4*)&s[c];
    }
}

// ---- Phase 3: GEMM partial[s] = A[:, slice] @ W[slice, o_tile], slice = 2 chunks of KS
__global__ __launch_bounds__(256) void smw_gemm4(
    const float* __restrict__ A, const float* __restrict__ W,
    float* __restrict__ partial, int in_features, int out_f, int krows, int Bsz) {
    __shared__ float As[64][KS + 4];
    __shared__ float Ws[KS][TILE_O];
    const int tid = threadIdx.x;
    const int tx = tid & 15;
    const int ty = tid >> 4;
    const int o_base = blockIdx.x * TILE_O;

    float acc[4][4] = {};
    #pragma unroll
    for (int half = 0; half < 2; ++half) {
        const int k0 = (blockIdx.y * 2 + half) * KS;
        __syncthreads();
        #pragma unroll
        for (int t = 0; t < 4; ++t) {
            int idx = t * 256 + tid;
            int b = idx >> 4;
            int c4 = (idx & 15) * 4;
            int gi = k0 + c4;
            float4 v = make_float4(0.f, 0.f, 0.f, 0.f);
            if (b < Bsz) {
                const float* src = A + (long long)b * in_features + gi;
                if (gi + 3 < krows) v = *(const float4*)src;
                else {
                    if (gi + 0 < krows) v.x = src[0];
                    if (gi + 1 < krows) v.y = src[1];
                    if (gi + 2 < krows) v.z = src[2];
                    if (gi + 3 < krows) v.w = src[3];
                }
            }
            *(float4*)&As[b][c4] = v;
        }
        #pragma unroll
        for (int t = 0; t < 4; ++t) {
            int idx = t * 256 + tid;
            int r = idx >> 4;
            int c4 = (idx & 15) * 4;
            int gi = k0 + r;
            int go = o_base + c4;
            float4 v = make_float4(0.f, 0.f, 0.f, 0.f);
            if (gi < krows) {
                const float* src = W + (long long)gi * out_f + go;
                if (go + 3 < out_f) v = *(const float4*)src;
                else {
                    if (go + 0 < out_f) v.x = src[0];
                    if (go + 1 < out_f) v.y = src[1];
                    if (go + 2 < out_f) v.z = src[2];
                    if (go + 3 < out_f) v.w = src[3];
                }
            }
            *(float4*)&Ws[r][c4] = v;
        }
        __syncthreads();

        #pragma unroll 8
        for (int i = 0; i < KS; ++i) {
            float4 w4 = *(const float4*)&Ws[i][tx * 4];
            float a[4];
            #pragma unroll
            for (int r = 0; r < 4; ++r) a[r] = As[ty * 4 + r][i];
            #pragma unroll
            for (int r = 0; r < 4; ++r) {
                acc[r][0] += a[r] * w4.x;
                acc[r][1] += a[r] * w4.y;
                acc[r][2] += a[r] * w4.z;
                acc[r][3] += a[r] * w4.w;
            }
        }
    }

    float* P = partial + (long long)blockIdx.y * 64 * PSTRIDE;
    #pragma unroll
    for (int r = 0; r < 4; ++r) {
        int b = ty * 4 + r;
        if (b < Bsz)
            *(float4*)&P[(long long)b * PSTRIDE + o_base + tx * 4] =
                make_float4(acc[r][0], acc[r][1], acc[r][2], acc[r][3]);
    }
}

// ---- Phase 4: out = bias + sum_s partial[s]  (float4 lanes)
__global__ void smw_reduce3(const float* __restrict__ partial,
                            const float* __restrict__ bias,
                            float* __restrict__ out, int out_f, int Bsz, int total4) {
    int idx = blockIdx.x * blockDim.x + threadIdx.x;
    if (idx >= total4) return;
    const int of4 = out_f >> 2;
    int b = idx / of4, o4 = idx - b * of4;
    const float4* B4 = (const float4*)bias;
    const float4* P4 = (const float4*)partial;
    float4 acc = B4[o4];
    #pragma unroll
    for (int s = 0; s < SLICES; ++s) {
        float4 v = P4[((long long)s * 64 + b) * (PSTRIDE >> 2) + o4];
        acc.x += v.x; acc.y += v.y; acc.z += v.z; acc.w += v.w;
    }
    ((float4*)out)[idx] = acc;
}

// ================= fallback path (round-1, known-good, needs only 16 MB ws) ==
__global__ void smw_build_fb(const int* __restrict__ mask, const float* __restrict__ wgt,
                             float* __restrict__ W, const int* __restrict__ flag,
                             int n_edges, int out_f) {
    int e = blockIdx.x * blockDim.x + threadIdx.x;
    if (e >= n_edges) return;
    int ci, co;
    if (*flag) {
        const long long* m64 = (const long long*)mask;
        ci = (int)m64[2 * (long long)e];
        co = (int)m64[2 * (long long)e + 1];
    } else {
        ci = mask[2 * e]; co = mask[2 * e + 1];
    }
    atomicAdd(&W[(long long)ci * out_f + co], wgt[e]);
}

__global__ void smw_init_out_fb(float* __restrict__ out, const float* __restrict__ bias,
                                int total, int out_f) {
    int idx = blockIdx.x * blockDim.x + threadIdx.x;
    if (idx < total) out[idx] = bias[idx % out_f];
}

__global__ __launch_bounds__(256) void smw_gemm_fb(
    const float* __restrict__ A, const float* __restrict__ W,
    float* __restrict__ out, int in_features, int out_f, int krows,
    int n_chunks, int Bsz) {
    __shared__ float As[64][36];
    __shared__ float Ws[32][64];
    const int tid = threadIdx.x;
    const int tx = tid & 15;
    const int ty = tid >> 4;
    const int o_base = blockIdx.x * 64;
    float acc[4][4] = {};
    for (int c = blockIdx.y; c < n_chunks; c += 8) {
        const int i0 = c * 32;
        __syncthreads();
        #pragma unroll
        for (int k = 0; k < 8; ++k) {
            int idx = k * 256 + tid;
            int i = idx & 31;
            int b = idx >> 5;
            float v = 0.0f;
            int gi = i0 + i;
            if (b < Bsz && gi < in_features) v = A[(long long)b * in_features + gi];
            As[b][i] = v;
        }
        #pragma unroll
        for (int k = 0; k < 8; ++k) {
            int idx = k * 256 + tid;
            int o = idx & 63;
            int i = idx >> 6;
            int gi = i0 + i;
            int go = o_base + o;
            Ws[i][o] = (gi < krows && go < out_f) ? W[(long long)gi * out_f + go] : 0.0f;
        }
        __syncthreads();
        #pragma unroll
        for (int i = 0; i < 32; ++i) {
            float4 w4 = *(const float4*)(&Ws[i][tx * 4]);
            float a[4];
            #pragma unroll
            for (int r = 0; r < 4; ++r) a[r] = As[ty * 4 + r][i];
            #pragma unroll
            for (int r = 0; r < 4; ++r) {
                acc[r][0] += a[r] * w4.x;
                acc[r][1] += a[r] * w4.y;
                acc[r][2] += a[r] * w4.z;
                acc[r][3] += a[r] * w4.w;
            }
        }
    }
    #pragma unroll
    for (int r = 0; r < 4; ++r) {
        int b = ty * 4 + r;
        if (b >= Bsz) continue;
        #pragma unroll
        for (int cc = 0; cc < 4; ++cc) {
            int o = o_base + tx * 4 + cc;
            if (o < out_f) atomicAdd(&out[(long long)b * out_f + o], acc[r][cc]);
        }
    }
}

// =============================================================================
static inline size_t align_up(size_t x, size_t a) { return (x + a - 1) & ~(a - 1); }

extern "C" void kernel_launch(void* const* d_in, const int* in_sizes, int n_in,
                              void* d_out, int out_size, void* d_ws, size_t ws_size,
                              hipStream_t stream) {
    const float* input = (const float*)d_in[0];
    const int*   mask  = (const int*)d_in[1];
    const float* wgt   = (const float*)d_in[2];
    const float* bias  = (const float*)d_in[3];
    float* out = (float*)d_out;

    const int out_f   = in_sizes[3];            // 2000
    const int n_edges = in_sizes[2];            // 2,000,000
    const int Bsz     = out_size / out_f;       // 64
    const int in_features = in_sizes[0] / Bsz;  // 20000
    const int krows   = out_f;                  // ci values < out_f per problem spec
    const int nbins   = (krows + ROWS8 - 1) / ROWS8;   // 250
    const int nseg    = (n_edges + SEG6 - 1) / SEG6;   // 245

    size_t W_bytes      = align_up((size_t)krows * out_f * 4, 1024);
    size_t binned_bytes = align_up((size_t)nseg * NB * CAP * 8, 1024);       // 32.1 MB
    size_t part_bytes   = align_up((size_t)SLICES * 64 * PSTRIDE * 4, 1024); // 8.4 MB
    size_t union_bytes  = binned_bytes > part_bytes ? binned_bytes : part_bytes;
    size_t counts_bytes = (size_t)NB * NSEGP * 4;    // 512 KB
    size_t ovf_bytes    = (size_t)OVF_CAP * 8;       // 32 KB
    size_t need_fast = W_bytes + union_bytes + counts_bytes + ovf_bytes + 4096;

    char* p = (char*)d_ws;
    float* W       = (float*)p;
    int2*  binned  = (int2*)(p + W_bytes);        // dead after bin_build
    float* partial = (float*)(p + W_bytes);       // same region, used after
    int*   counts  = (int*)(p + W_bytes + union_bytes);
    int2*  ovf     = (int2*)(p + W_bytes + union_bytes + counts_bytes);
    int*   ovf_cnt = (int*)(p + W_bytes + union_bytes + counts_bytes + ovf_bytes);
    int*   flag    = ovf_cnt + 32;

    const size_t sc_lds  = (size_t)NB * 4 + (size_t)NB * SCAP * 8;   // 99,328 B
    const size_t bb_lds  = (size_t)ROWS8 * out_f * 4;                // <= 64 KB
    const bool fast = (ws_size >= need_fast) && out_f <= 2048 && (out_f & 3) == 0 &&
                      krows <= 2048 && nbins <= NB && Bsz <= 64 && n_edges >= 1 &&
                      nseg <= NSEGP && bb_lds <= 65536 && (out_size & 3) == 0;

    if (fast) {
        hipMemsetAsync(ovf_cnt, 0, sizeof(int), stream);
        smw_detect<<<1, 64, 0, stream>>>((const unsigned int*)mask, flag);
        smw_scatter6<<<nseg, TPB_SC, sc_lds, stream>>>(mask, wgt, flag, binned,
                                                       counts, ovf, ovf_cnt,
                                                       n_edges, krows, nbins);
        smw_bin_build4<<<nbins, 512, bb_lds, stream>>>(binned, counts, ovf, ovf_cnt,
                                                       W, out_f, krows, nseg);
        dim3 grid((out_f + TILE_O - 1) / TILE_O, SLICES);         // 32 x 16
        smw_gemm4<<<grid, 256, 0, stream>>>(input, W, partial, in_features, out_f,
                                            krows, Bsz);
        int total4 = out_size >> 2;
        smw_reduce3<<<(total4 + 255) / 256, 256, 0, stream>>>(partial, bias, out,
                                                              out_f, Bsz, total4);
    } else {
        // round-1 known-good path (16 MB + flag)
        int* flag_fb = (int*)(p + (size_t)krows * out_f * 4);
        hipMemsetAsync(d_ws, 0, (size_t)krows * out_f * 4, stream);
        smw_detect<<<1, 64, 0, stream>>>((const unsigned int*)mask, flag_fb);
        smw_build_fb<<<(n_edges + 255) / 256, 256, 0, stream>>>(mask, wgt, W, flag_fb,
                                                                n_edges, out_f);
        smw_init_out_fb<<<(out_size + 255) / 256, 256, 0, stream>>>(out, bias, out_size, out_f);
        const int n_chunks = (krows + 31) / 32;
        dim3 grid((out_f + 63) / 64, 8);
        smw_gemm_fb<<<grid, 256, 0, stream>>>(input, W, out, in_features, out_f,
                                              krows, n_chunks, Bsz);
    }
}

// Round 9
// 61.902 us; speedup vs baseline: 1.1924x; 1.1924x over previous
//
#include <hip/hip_runtime.h>

// SparseMaskedLinear: out[b,co] = bias[co] + sum_e in[b,ci_e]*w_e  (B=64, dims 2000)
// Dense reformulation: W[ci][co] = sum w_e;  out = in[:, :2000] @ W + bias.
// Round-9: scatter restructured for MLP: phase 1 preloads ALL 8 edges/thread into
// registers (8 outstanding dwordx4 loads; R3 evidence: fused loop compiled to
// VGPR=12 -> serialized ~900cy round trips). Phase 2 ranks+stages. SCAP 24 ->
// 50 KB LDS -> 3 blocks/CU. init kernel folds cursor-zero + int64-detect.

#define ROWS8 8
#define NB 256                 // hist/stage slots (nbins <= 256)
#define CUR_STRIDE 32          // one cursor per 128 B line
#define BIN_CAPB 10752         // per-bin cap: mean ~9950 incl pads, ~9 sigma headroom
#define E_PT 8
#define TPB_SC 512
#define SEG5 (TPB_SC * E_PT)   // 4096 edges per scatter block
#define SCAP 24                // staged records per bin per block (mean 16.4)

#define TILE_O 64
#define KS 64
#define SLICES 16
#define PSTRIDE 2048

// ---- fused init: zero padded cursors + int64-vs-int32 detect (one wave ballot)
__global__ void smw_init(const unsigned int* __restrict__ m, int n_edges,
                         int* __restrict__ cursor, int* __restrict__ flag, int nbins) {
    const int t = threadIdx.x;
    if (t < nbins) cursor[t * CUR_STRIDE] = 0;
    if (t < 64) {
        unsigned v = (t < n_edges) ? m[2 * t + 1] : 0u;
        unsigned long long bal = __ballot(v != 0u);
        if (t == 0) *flag = (bal == 0ull) ? 1 : 0;   // all-high-words-zero => int64
    }
}

// ---- Phase 1: MLP-forced scatter. Load phase: all E_PT edges into registers
// (independent loads -> deep vmcnt pipeline). Rank phase: LDS atomic rank ->
// stage (r<SCAP) or carry for post-reserve direct store. One padded cursor
// atomicAdd per (bin,block), then 16-lane-group 128B-aligned flush.
__global__ __launch_bounds__(TPB_SC) void smw_scatter7(
    const int* __restrict__ mask, const float* __restrict__ wgt,
    const int* __restrict__ flag, int* __restrict__ cursor,
    int2* __restrict__ binned, int n_edges, int krows, int nbins) {
    __shared__ int hist[NB];
    __shared__ int sbase[NB];
    __shared__ int2 stage[NB * SCAP];          // 49,152 B
    const int tid = threadIdx.x;
    const long long e0 = (long long)blockIdx.x * SEG5;
    if (tid < NB) hist[tid] = 0;
    __syncthreads();
    const bool is64 = (*flag != 0);

    // ---- load phase: fill registers with 8 independent edges
    int ci[E_PT], co[E_PT]; float wv[E_PT];
    if (is64) {
        #pragma unroll
        for (int i = 0; i < E_PT; ++i) {
            long long e = e0 + (long long)i * TPB_SC + tid;
            ci[i] = -1; co[i] = 0;
            if (e < n_edges) { int4 mm = ((const int4*)mask)[e]; ci[i] = mm.x; co[i] = mm.z; }
        }
    } else {
        #pragma unroll
        for (int i = 0; i < E_PT; ++i) {
            long long e = e0 + (long long)i * TPB_SC + tid;
            ci[i] = -1; co[i] = 0;
            if (e < n_edges) { int2 mm = ((const int2*)mask)[e]; ci[i] = mm.x; co[i] = mm.y; }
        }
    }
    #pragma unroll
    for (int i = 0; i < E_PT; ++i) {
        long long e = e0 + (long long)i * TPB_SC + tid;
        wv[i] = (e < n_edges) ? wgt[e] : 0.0f;
    }

    // ---- rank + stage phase
    int pk[E_PT];                               // (bin<<16)|rank for overflow, -1 = done
    #pragma unroll
    for (int i = 0; i < E_PT; ++i) {
        pk[i] = -1;
        if ((unsigned)ci[i] < (unsigned)krows) {
            int b = ci[i] >> 3;                 // 8 rows per bin
            int2 rec = make_int2((int)((((unsigned)(ci[i] & 7)) << 16) |
                                       (unsigned)(co[i] & 0xFFFF)),
                                 __float_as_int(wv[i]));
            int r = atomicAdd(&hist[b], 1);     // LDS rank, r < 4096
            if (r < SCAP) stage[b * SCAP + r] = rec;
            else          pk[i] = (b << 16) | r;   // rare (~3% tail)
        }
    }
    __syncthreads();
    if (tid < nbins) {
        int c = hist[tid];
        int cp = (c + 7) & ~7;                  // 64B-aligned reservation
        sbase[tid] = cp ? atomicAdd(&cursor[tid * CUR_STRIDE], cp) : 0;
    }
    __syncthreads();
    // overflow direct writes (rare)
    #pragma unroll
    for (int i = 0; i < E_PT; ++i) {
        if (pk[i] >= 0) {
            int b = pk[i] >> 16, r = pk[i] & 0xFFFF;
            long long pos = (long long)sbase[b] + r;
            if (pos < BIN_CAPB)
                binned[(long long)b * BIN_CAPB + pos] =
                    make_int2((int)((((unsigned)(ci[i] & 7)) << 16) |
                                    (unsigned)(co[i] & 0xFFFF)),
                              __float_as_int(wv[i]));
        }
    }
    // cooperative aligned flush: 32 groups x 16 lanes
    const int grp = tid >> 4;
    const int ln  = tid & 15;
    for (int b = grp; b < nbins; b += (TPB_SC / 16)) {
        int c  = hist[b];
        int cS = c < SCAP ? c : SCAP;
        int cp = (c + 7) & ~7;
        int bs = sbase[b];
        long long bb = (long long)b * BIN_CAPB;
        for (int k = ln; k < cp; k += 16) {
            if (bs + k >= BIN_CAPB) break;
            if (k < cS)
                binned[bb + bs + k] = stage[b * SCAP + k];
            else if (k >= c)
                binned[bb + bs + k] = make_int2(0, 0);  // zero-weight no-op pad
            // cS <= k < c: overflow region, written above
        }
    }
}

// ---- Phase 2: per-bin exclusive build of 8 W-rows in dynamic LDS, plain stores.
__global__ __launch_bounds__(512) void smw_bin_build3(
    const int2* __restrict__ binned, const int* __restrict__ cursor,
    float* __restrict__ W, int out_f, int krows) {
    extern __shared__ float tile[];                 // ROWS8 * out_f floats (<= 64 KB)
    const int tid = threadIdx.x;
    const int bin = blockIdx.x;
    const int tile_elems = ROWS8 * out_f;
    {
        float4* t4 = (float4*)tile;
        int n4 = tile_elems >> 2;
        for (int t = tid; t < n4; t += 512) t4[t] = make_float4(0.f, 0.f, 0.f, 0.f);
    }
    __syncthreads();
    int n = cursor[bin * CUR_STRIDE];
    if (n > BIN_CAPB) n = BIN_CAPB;
    const int2* src = binned + (long long)bin * BIN_CAPB;
    for (int i = tid; i < n; i += 512) {
        int2 rec = src[i];
        unsigned k = (unsigned)rec.x;
        atomicAdd(&tile[(int)(k >> 16) * out_f + (int)(k & 0xFFFFu)],
                  __int_as_float(rec.y));           // ds_add_f32; pads add +0 to [0]
    }
    __syncthreads();
    #pragma unroll
    for (int r = 0; r < ROWS8; ++r) {
        int row = bin * ROWS8 + r;
        if (row >= krows) break;
        float* dst = W + (long long)row * out_f;
        const float* s = tile + r * out_f;
        for (int c = tid * 4; c < out_f; c += 2048)
            *(float4*)&dst[c] = *(const float4*)&s[c];
    }
}

// ---- Phase 3: GEMM partial[s] = A[:, slice] @ W[slice, o_tile], slice = 2 chunks of KS
__global__ __launch_bounds__(256) void smw_gemm4(
    const float* __restrict__ A, const float* __restrict__ W,
    float* __restrict__ partial, int in_features, int out_f, int krows, int Bsz) {
    __shared__ float As[64][KS + 4];
    __shared__ float Ws[KS][TILE_O];
    const int tid = threadIdx.x;
    const int tx = tid & 15;
    const int ty = tid >> 4;
    const int o_base = blockIdx.x * TILE_O;

    float acc[4][4] = {};
    #pragma unroll
    for (int half = 0; half < 2; ++half) {
        const int k0 = (blockIdx.y * 2 + half) * KS;
        __syncthreads();
        #pragma unroll
        for (int t = 0; t < 4; ++t) {
            int idx = t * 256 + tid;
            int b = idx >> 4;
            int c4 = (idx & 15) * 4;
            int gi = k0 + c4;
            float4 v = make_float4(0.f, 0.f, 0.f, 0.f);
            if (b < Bsz) {
                const float* src = A + (long long)b * in_features + gi;
                if (gi + 3 < krows) v = *(const float4*)src;
                else {
                    if (gi + 0 < krows) v.x = src[0];
                    if (gi + 1 < krows) v.y = src[1];
                    if (gi + 2 < krows) v.z = src[2];
                    if (gi + 3 < krows) v.w = src[3];
                }
            }
            *(float4*)&As[b][c4] = v;
        }
        #pragma unroll
        for (int t = 0; t < 4; ++t) {
            int idx = t * 256 + tid;
            int r = idx >> 4;
            int c4 = (idx & 15) * 4;
            int gi = k0 + r;
            int go = o_base + c4;
            float4 v = make_float4(0.f, 0.f, 0.f, 0.f);
            if (gi < krows) {
                const float* src = W + (long long)gi * out_f + go;
                if (go + 3 < out_f) v = *(const float4*)src;
                else {
                    if (go + 0 < out_f) v.x = src[0];
                    if (go + 1 < out_f) v.y = src[1];
                    if (go + 2 < out_f) v.z = src[2];
                    if (go + 3 < out_f) v.w = src[3];
                }
            }
            *(float4*)&Ws[r][c4] = v;
        }
        __syncthreads();

        #pragma unroll 8
        for (int i = 0; i < KS; ++i) {
            float4 w4 = *(const float4*)&Ws[i][tx * 4];
            float a[4];
            #pragma unroll
            for (int r = 0; r < 4; ++r) a[r] = As[ty * 4 + r][i];
            #pragma unroll
            for (int r = 0; r < 4; ++r) {
                acc[r][0] += a[r] * w4.x;
                acc[r][1] += a[r] * w4.y;
                acc[r][2] += a[r] * w4.z;
                acc[r][3] += a[r] * w4.w;
            }
        }
    }

    float* P = partial + (long long)blockIdx.y * 64 * PSTRIDE;
    #pragma unroll
    for (int r = 0; r < 4; ++r) {
        int b = ty * 4 + r;
        if (b < Bsz)
            *(float4*)&P[(long long)b * PSTRIDE + o_base + tx * 4] =
                make_float4(acc[r][0], acc[r][1], acc[r][2], acc[r][3]);
    }
}

// ---- Phase 4: out = bias + sum_s partial[s]  (float4 lanes)
__global__ void smw_reduce3(const float* __restrict__ partial,
                            const float* __restrict__ bias,
                            float* __restrict__ out, int out_f, int Bsz, int total4) {
    int idx = blockIdx.x * blockDim.x + threadIdx.x;
    if (idx >= total4) return;
    const int of4 = out_f >> 2;
    int b = idx / of4, o4 = idx - b * of4;
    const float4* B4 = (const float4*)bias;
    const float4* P4 = (const float4*)partial;
    float4 acc = B4[o4];
    #pragma unroll
    for (int s = 0; s < SLICES; ++s) {
        float4 v = P4[((long long)s * 64 + b) * (PSTRIDE >> 2) + o4];
        acc.x += v.x; acc.y += v.y; acc.z += v.z; acc.w += v.w;
    }
    ((float4*)out)[idx] = acc;
}

// ================= fallback path (round-1, known-good, needs only 16 MB ws) ==
__global__ void smw_detect(const unsigned int* __restrict__ m, int* __restrict__ flag) {
    if (blockIdx.x == 0 && threadIdx.x == 0) {
        unsigned int orv = 0u;
        for (int k = 0; k < 64; ++k) orv |= m[2 * k + 1];
        *flag = (orv == 0u) ? 1 : 0;
    }
}

__global__ void smw_build_fb(const int* __restrict__ mask, const float* __restrict__ wgt,
                             float* __restrict__ W, const int* __restrict__ flag,
                             int n_edges, int out_f) {
    int e = blockIdx.x * blockDim.x + threadIdx.x;
    if (e >= n_edges) return;
    int ci, co;
    if (*flag) {
        const long long* m64 = (const long long*)mask;
        ci = (int)m64[2 * (long long)e];
        co = (int)m64[2 * (long long)e + 1];
    } else {
        ci = mask[2 * e]; co = mask[2 * e + 1];
    }
    atomicAdd(&W[(long long)ci * out_f + co], wgt[e]);
}

__global__ void smw_init_out_fb(float* __restrict__ out, const float* __restrict__ bias,
                                int total, int out_f) {
    int idx = blockIdx.x * blockDim.x + threadIdx.x;
    if (idx < total) out[idx] = bias[idx % out_f];
}

__global__ __launch_bounds__(256) void smw_gemm_fb(
    const float* __restrict__ A, const float* __restrict__ W,
    float* __restrict__ out, int in_features, int out_f, int krows,
    int n_chunks, int Bsz) {
    __shared__ float As[64][36];
    __shared__ float Ws[32][64];
    const int tid = threadIdx.x;
    const int tx = tid & 15;
    const int ty = tid >> 4;
    const int o_base = blockIdx.x * 64;
    float acc[4][4] = {};
    for (int c = blockIdx.y; c < n_chunks; c += 8) {
        const int i0 = c * 32;
        __syncthreads();
        #pragma unroll
        for (int k = 0; k < 8; ++k) {
            int idx = k * 256 + tid;
            int i = idx & 31;
            int b = idx >> 5;
            float v = 0.0f;
            int gi = i0 + i;
            if (b < Bsz && gi < in_features) v = A[(long long)b * in_features + gi];
            As[b][i] = v;
        }
        #pragma unroll
        for (int k = 0; k < 8; ++k) {
            int idx = k * 256 + tid;
            int o = idx & 63;
            int i = idx >> 6;
            int gi = i0 + i;
            int go = o_base + o;
            Ws[i][o] = (gi < krows && go < out_f) ? W[(long long)gi * out_f + go] : 0.0f;
        }
        __syncthreads();
        #pragma unroll
        for (int i = 0; i < 32; ++i) {
            float4 w4 = *(const float4*)(&Ws[i][tx * 4]);
            float a[4];
            #pragma unroll
            for (int r = 0; r < 4; ++r) a[r] = As[ty * 4 + r][i];
            #pragma unroll
            for (int r = 0; r < 4; ++r) {
                acc[r][0] += a[r] * w4.x;
                acc[r][1] += a[r] * w4.y;
                acc[r][2] += a[r] * w4.z;
                acc[r][3] += a[r] * w4.w;
            }
        }
    }
    #pragma unroll
    for (int r = 0; r < 4; ++r) {
        int b = ty * 4 + r;
        if (b >= Bsz) continue;
        #pragma unroll
        for (int cc = 0; cc < 4; ++cc) {
            int o = o_base + tx * 4 + cc;
            if (o < out_f) atomicAdd(&out[(long long)b * out_f + o], acc[r][cc]);
        }
    }
}

// =============================================================================
static inline size_t align_up(size_t x, size_t a) { return (x + a - 1) & ~(a - 1); }

extern "C" void kernel_launch(void* const* d_in, const int* in_sizes, int n_in,
                              void* d_out, int out_size, void* d_ws, size_t ws_size,
                              hipStream_t stream) {
    const float* input = (const float*)d_in[0];
    const int*   mask  = (const int*)d_in[1];
    const float* wgt   = (const float*)d_in[2];
    const float* bias  = (const float*)d_in[3];
    float* out = (float*)d_out;

    const int out_f   = in_sizes[3];            // 2000
    const int n_edges = in_sizes[2];            // 2,000,000
    const int Bsz     = out_size / out_f;       // 64
    const int in_features = in_sizes[0] / Bsz;  // 20000
    const int krows   = out_f;                  // ci values < out_f per problem spec
    const int nbins   = (krows + ROWS8 - 1) / ROWS8;   // 250

    size_t W_bytes      = align_up((size_t)krows * out_f * 4, 1024);
    size_t binned_bytes = align_up((size_t)nbins * BIN_CAPB * 8, 1024);   // 21.5 MB
    size_t part_bytes   = align_up((size_t)SLICES * 64 * PSTRIDE * 4, 1024);
    size_t union_bytes  = binned_bytes > part_bytes ? binned_bytes : part_bytes;
    size_t cursor_bytes = (size_t)NB * CUR_STRIDE * 4;   // 32 KB padded cursors
    size_t meta_bytes   = cursor_bytes + 4096;
    size_t need_fast = W_bytes + union_bytes + meta_bytes;

    char* p = (char*)d_ws;
    float* W      = (float*)p;
    int2*  binned = (int2*)(p + W_bytes);         // dead after bin_build
    float* partial= (float*)(p + W_bytes);        // same region, used after
    int*   cursor = (int*)(p + W_bytes + union_bytes);
    int*   flag   = (int*)(p + W_bytes + union_bytes + cursor_bytes);

    const size_t bb_lds = (size_t)ROWS8 * out_f * 4;   // <= 64 KB when out_f <= 2048
    const bool fast = (ws_size >= need_fast) && out_f <= 2048 && (out_f & 3) == 0 &&
                      krows <= 2048 && nbins <= NB && Bsz <= 64 && n_edges >= 1 &&
                      bb_lds <= 65536 && (out_size & 3) == 0;

    if (fast) {
        smw_init<<<1, 256, 0, stream>>>((const unsigned int*)mask, n_edges,
                                        cursor, flag, nbins);
        int nseg = (n_edges + SEG5 - 1) / SEG5;                   // 489
        smw_scatter7<<<nseg, TPB_SC, 0, stream>>>(mask, wgt, flag, cursor, binned,
                                                  n_edges, krows, nbins);
        smw_bin_build3<<<nbins, 512, bb_lds, stream>>>(binned, cursor, W, out_f, krows);
        dim3 grid((out_f + TILE_O - 1) / TILE_O, SLICES);         // 32 x 16
        smw_gemm4<<<grid, 256, 0, stream>>>(input, W, partial, in_features, out_f,
                                            krows, Bsz);
        int total4 = out_size >> 2;
        smw_reduce3<<<(total4 + 255) / 256, 256, 0, stream>>>(partial, bias, out,
                                                              out_f, Bsz, total4);
    } else {
        // round-1 known-good path (16 MB + flag)
        int* flag_fb = (int*)(p + (size_t)krows * out_f * 4);
        hipMemsetAsync(d_ws, 0, (size_t)krows * out_f * 4, stream);
        smw_detect<<<1, 64, 0, stream>>>((const unsigned int*)mask, flag_fb);
        smw_build_fb<<<(n_edges + 255) / 256, 256, 0, stream>>>(mask, wgt, W, flag_fb,
                                                                n_edges, out_f);
        smw_init_out_fb<<<(out_size + 255) / 256, 256, 0, stream>>>(out, bias, out_size, out_f);
        const int n_chunks = (krows + 31) / 32;
        dim3 grid((out_f + 63) / 64, 8);
        smw_gemm_fb<<<grid, 256, 0, stream>>>(input, W, out, in_features, out_f,
                                              krows, n_chunks, Bsz);
    }
}